// Round 1
// baseline (452.255 us; speedup 1.0000x reference)
//
#include <hip/hip_runtime.h>

// Geometry (fixed by the problem)
constexpr int B_ = 4, CIN_ = 8, Hd = 64, Wd = 64;
constexpr int COUT_ = 32, KH_ = 3, KW_ = 3;
constexpr int K_ = CIN_ * KH_ * KW_;      // 72
constexpr int L_ = Hd * Wd;               // 4096
constexpr int POT_SIZE = B_ * COUT_ * L_; // 524288 (also the k-stride of traces_folded)

// One thread handles (b, o, l..l+3). Loops over k=(c,kh,kw):
//   - float4 loads of trace/delay/delay_init at [b,o,k,l]   (contiguous in l)
//   - float4 store of trace_new to out[POT + k*POT_SIZE + bo*L + l]
//   - pot += (delay + xu*delay_init == 1) ? w[o,k] : 0
// xu (im2col of binary x) recomputed on the fly from the 0.5 MB x (cache-hot).
__global__ __launch_bounds__(256)
void fused_conv_delay_trace(const float* __restrict__ x,
                            const float* __restrict__ weight,
                            const float* __restrict__ trace,
                            const float* __restrict__ delay,
                            const float* __restrict__ delay_init,
                            const float* __restrict__ alpha_p,
                            const float* __restrict__ tau_p,
                            const float* __restrict__ dt_p,
                            float* __restrict__ out)
{
    const float alpha = alpha_p[0];
    const float r = dt_p[0] / tau_p[0];

    const int bo    = blockIdx.x >> 2;        // b*COUT + o   (0..127)
    const int chunk = blockIdx.x & 3;         // quarter of L
    const int l     = chunk * 1024 + threadIdx.x * 4;
    const int b  = bo >> 5;                   // / COUT
    const int o  = bo & 31;                   // % COUT
    const int ho = l >> 6;
    const int wo = l & 63;

    const float* xb   = x + b * (CIN_ * Hd * Wd);
    const float* wrow = weight + o * K_;

    const int base = bo * (K_ * L_) + l;      // into [B,COUT,K,L]
    const float* tptr  = trace + base;
    const float* dptr  = delay + base;
    const float* diptr = delay_init + base;
    float* tout = out + POT_SIZE + bo * L_ + l;   // traces_folded, k-stride = POT_SIZE

    float4 pot = make_float4(0.f, 0.f, 0.f, 0.f);

    int k = 0;
    for (int c = 0; c < CIN_; ++c) {
        const float* xc = xb + c * (Hd * Wd);
        #pragma unroll
        for (int kh = 0; kh < KH_; ++kh) {
            const int h = ho - 1 + kh;
            const bool hok = (unsigned)h < (unsigned)Hd;
            const float* xr = xc + h * Wd;
            // x row segment w = wo-1 .. wo+4 (covers kw=0..2, j=0..3)
            float xv[6];
            #pragma unroll
            for (int j = 0; j < 6; ++j) {
                const int w = wo - 1 + j;
                xv[j] = (hok && (unsigned)w < (unsigned)Wd) ? xr[w] : 0.0f;
            }
            #pragma unroll
            for (int kw = 0; kw < KW_; ++kw, ++k) {
                const float4 d  = *reinterpret_cast<const float4*>(dptr  + k * L_);
                const float4 t  = *reinterpret_cast<const float4*>(tptr  + k * L_);
                const float4 di = *reinterpret_cast<const float4*>(diptr + k * L_);
                const float wk = wrow[k];
                const float xu0 = xv[kw + 0];
                const float xu1 = xv[kw + 1];
                const float xu2 = xv[kw + 2];
                const float xu3 = xv[kw + 3];
                float4 tn;
                tn.x = t.x + r * (alpha * xu0 - t.x);
                tn.y = t.y + r * (alpha * xu1 - t.y);
                tn.z = t.z + r * (alpha * xu2 - t.z);
                tn.w = t.w + r * (alpha * xu3 - t.w);
                *reinterpret_cast<float4*>(tout + k * POT_SIZE) = tn;
                pot.x += (d.x + xu0 * di.x == 1.0f) ? wk : 0.0f;
                pot.y += (d.y + xu1 * di.y == 1.0f) ? wk : 0.0f;
                pot.z += (d.z + xu2 * di.z == 1.0f) ? wk : 0.0f;
                pot.w += (d.w + xu3 * di.w == 1.0f) ? wk : 0.0f;
            }
        }
    }
    *reinterpret_cast<float4*>(out + bo * L_ + l) = pot;
}

extern "C" void kernel_launch(void* const* d_in, const int* in_sizes, int n_in,
                              void* d_out, int out_size, void* d_ws, size_t ws_size,
                              hipStream_t stream) {
    const float* x          = (const float*)d_in[0];
    const float* weight     = (const float*)d_in[1];
    const float* trace      = (const float*)d_in[2];
    const float* delay      = (const float*)d_in[3];
    const float* delay_init = (const float*)d_in[4];
    const float* alpha_t    = (const float*)d_in[5];
    const float* tau_t      = (const float*)d_in[6];
    const float* dt         = (const float*)d_in[7];
    float* out = (float*)d_out;

    const int total_threads = B_ * COUT_ * (L_ / 4);   // 131072
    dim3 grid(total_threads / 256);                    // 512 blocks
    fused_conv_delay_trace<<<grid, 256, 0, stream>>>(
        x, weight, trace, delay, delay_init, alpha_t, tau_t, dt, out);
}

// Round 3
// 432.990 us; speedup vs baseline: 1.0445x; 1.0445x over previous
//
#include <hip/hip_runtime.h>

// Geometry (fixed by the problem)
constexpr int B_ = 4, CIN_ = 8, Hd = 64, Wd = 64;
constexpr int COUT_ = 32, KH_ = 3, KW_ = 3;
constexpr int K_ = CIN_ * KH_ * KW_;      // 72
constexpr int L_ = Hd * Wd;               // 4096
constexpr int POT_SIZE = B_ * COUT_ * L_; // 524288 (also the k-stride of traces_folded)

// Native vector type for nontemporal builtins (HIP float4 is a struct and
// is rejected by __builtin_nontemporal_*).
typedef float v4f __attribute__((ext_vector_type(4)));

// Split the K=72 reduction into NCHUNK chunks of CIN_/NCHUNK input channels.
// One thread handles (chunk, b, o, l..l+3); partial pot goes in via atomicAdd
// (pot region pre-zeroed by hipMemsetAsync). 2048 blocks -> 32 waves/CU.
constexpr int NCHUNK = 4;
constexpr int C_PER_CHUNK = CIN_ / NCHUNK;   // 2

__global__ __launch_bounds__(256)
void fused_conv_delay_trace(const float* __restrict__ x,
                            const float* __restrict__ weight,
                            const float* __restrict__ trace,
                            const float* __restrict__ delay,
                            const float* __restrict__ delay_init,
                            const float* __restrict__ alpha_p,
                            const float* __restrict__ tau_p,
                            const float* __restrict__ dt_p,
                            float* __restrict__ out)
{
    const float alpha = alpha_p[0];
    const float r = dt_p[0] / tau_p[0];

    const int bid   = blockIdx.x;
    const int chunk = bid >> 9;               // 0..NCHUNK-1
    const int rem   = bid & 511;
    const int bo    = rem >> 2;               // b*COUT + o   (0..127)
    const int qrt   = rem & 3;                // quarter of L
    const int l     = qrt * 1024 + threadIdx.x * 4;
    const int b  = bo >> 5;                   // / COUT
    const int o  = bo & 31;                   // % COUT
    const int ho = l >> 6;
    const int wo = l & 63;

    const float* xb   = x + b * (CIN_ * Hd * Wd);
    const float* wrow = weight + o * K_;

    const int base = bo * (K_ * L_) + l;      // into [B,COUT,K,L]
    const float* tptr  = trace + base;
    const float* dptr  = delay + base;
    const float* diptr = delay_init + base;
    float* tout = out + POT_SIZE + bo * L_ + l;   // traces_folded, k-stride = POT_SIZE

    float px = 0.f, py = 0.f, pz = 0.f, pw = 0.f;

    const int c0 = chunk * C_PER_CHUNK;
    int k = c0 * (KH_ * KW_);
    for (int ci = 0; ci < C_PER_CHUNK; ++ci) {
        const float* xc = xb + (c0 + ci) * (Hd * Wd);
        #pragma unroll
        for (int kh = 0; kh < KH_; ++kh) {
            const int h = ho - 1 + kh;
            const bool hok = (unsigned)h < (unsigned)Hd;
            const float* xr = xc + h * Wd;
            // x row segment w = wo-1 .. wo+4 (covers kw=0..2, j=0..3)
            float xv[6];
            #pragma unroll
            for (int j = 0; j < 6; ++j) {
                const int w = wo - 1 + j;
                xv[j] = (hok && (unsigned)w < (unsigned)Wd) ? xr[w] : 0.0f;
            }
            #pragma unroll
            for (int kw = 0; kw < KW_; ++kw, ++k) {
                const v4f d  = __builtin_nontemporal_load(
                    reinterpret_cast<const v4f*>(dptr  + k * L_));
                const v4f t  = __builtin_nontemporal_load(
                    reinterpret_cast<const v4f*>(tptr  + k * L_));
                const v4f di = __builtin_nontemporal_load(
                    reinterpret_cast<const v4f*>(diptr + k * L_));
                const float wk = wrow[k];
                const float xu0 = xv[kw + 0];
                const float xu1 = xv[kw + 1];
                const float xu2 = xv[kw + 2];
                const float xu3 = xv[kw + 3];
                v4f tn;
                tn.x = t.x + r * (alpha * xu0 - t.x);
                tn.y = t.y + r * (alpha * xu1 - t.y);
                tn.z = t.z + r * (alpha * xu2 - t.z);
                tn.w = t.w + r * (alpha * xu3 - t.w);
                __builtin_nontemporal_store(tn,
                    reinterpret_cast<v4f*>(tout + k * POT_SIZE));
                px += (d.x + xu0 * di.x == 1.0f) ? wk : 0.0f;
                py += (d.y + xu1 * di.y == 1.0f) ? wk : 0.0f;
                pz += (d.z + xu2 * di.z == 1.0f) ? wk : 0.0f;
                pw += (d.w + xu3 * di.w == 1.0f) ? wk : 0.0f;
            }
        }
    }

    float* p = out + bo * L_ + l;
    atomicAdd(p + 0, px);
    atomicAdd(p + 1, py);
    atomicAdd(p + 2, pz);
    atomicAdd(p + 3, pw);
}

extern "C" void kernel_launch(void* const* d_in, const int* in_sizes, int n_in,
                              void* d_out, int out_size, void* d_ws, size_t ws_size,
                              hipStream_t stream) {
    const float* x          = (const float*)d_in[0];
    const float* weight     = (const float*)d_in[1];
    const float* trace      = (const float*)d_in[2];
    const float* delay      = (const float*)d_in[3];
    const float* delay_init = (const float*)d_in[4];
    const float* alpha_t    = (const float*)d_in[5];
    const float* tau_t      = (const float*)d_in[6];
    const float* dt         = (const float*)d_in[7];
    float* out = (float*)d_out;

    // zero the pot region (first POT_SIZE floats); trace region is fully
    // overwritten by the kernel's stores.
    (void)hipMemsetAsync(out, 0, POT_SIZE * sizeof(float), stream);

    const int blocks = NCHUNK * B_ * COUT_ * (L_ / 4) / 256;  // 2048
    fused_conv_delay_trace<<<blocks, 256, 0, stream>>>(
        x, weight, trace, delay, delay_init, alpha_t, tau_t, dt, out);
}